// Round 3
// baseline (358.509 us; speedup 1.0000x reference)
//
#include <hip/hip_runtime.h>
#include <cmath>

typedef __bf16 bf16x8 __attribute__((ext_vector_type(8)));
typedef __bf16 bf16x4 __attribute__((ext_vector_type(4)));
typedef float  f32x4  __attribute__((ext_vector_type(4)));

#define MFMA16(a,b,c) __builtin_amdgcn_mfma_f32_16x16x32_bf16((a),(b),(c),0,0,0)

// DIM=96 NH=3 HEAD=32 WS=7 SHIFT=3 P=5 H=W=56 NWH=NWW=8 NW=64 TP=320 N=54 HIDDEN=384 B=64
#define SCALE_Q 0.17677669529663687f   // 32^-0.5

// MFMA fact (m89-verified, matches round-2 behavior): C row (quad*4+r) = A-operand row
// index; C col (l15) = B-operand row index; A/B frag: row=l15, k=quad*8+j.
// We put the TOKEN operand in B everywhere possible so outputs land lane-row = own token.

// LDS strides (bf16 elems)
#define KST 104  // kt rows / scratch rows: 52 dw % 32 = 20 -> 2-way (free)
#define VP  68   // vT rows: 34 dw % 32 = 2 -> 2-way (free)

// LDS map (79360 B -> 2 blocks/CU), one block = TWO windows (wx=0,1):
//  kt[wx] = smem + wx*13312          [64 tok][KST] bf16  (P2 -> P3)
//  vT[wx] = smem + 26624 + wx*13056  [96 d][VP]   bf16  (P2 -> P5)
//  sw     = smem + 52736 + (wv*2+wx)*3328  per-wave [16][KST] scratch (wave-private)

// ---------------- prep: weight convert (fp32 -> bf16 [n][k]) + bias/mask table ----------------
// Table layout [cls(2x2)][h(3)][q(64)][k(64)] fp32 (k fast) -> lane reads float4 over k.
__global__ __launch_bounds__(256) void prep(const float* __restrict__ qkv_w,
                                            const float* __restrict__ proj_w,
                                            const float* __restrict__ fc1_w,
                                            const float* __restrict__ fc2_w,
                                            const float* __restrict__ rpb,
                                            __bf16* __restrict__ ws,
                                            float* __restrict__ tbl)
{
    int i = blockIdx.x * 256 + threadIdx.x;   // grid covers 110592 exactly
    {
        int j = i;
        if (j < 27648) {                       // qkv_w (96,288) -> [c][k], fold q-scale
            int c = j / 96, k = j % 96;
            float v = qkv_w[k * 288 + c];
            if (c < 96) v *= SCALE_Q;
            ws[j] = (__bf16)v;
        } else if ((j -= 27648) < 9216) {      // proj_w (96,96)
            int c = j / 96, k = j % 96;
            ws[27648 + j] = (__bf16)proj_w[k * 96 + c];
        } else if ((j -= 9216) < 36864) {      // fc1_w (96,384)
            int c = j / 96, k = j % 96;
            ws[36864 + j] = (__bf16)fc1_w[k * 384 + c];
        } else if ((j -= 36864) < 36864) {     // fc2_w (384,96)
            int c = j / 384, k = j % 384;
            ws[73728 + j] = (__bf16)fc2_w[k * 96 + c];
        }
    }
    if (i < 49152) {                           // [cls][h][q][k] fp32
        int k_ = i & 63, q_ = (i >> 6) & 63, h = (i >> 12) % 3, cls = i / 12288;
        float v;
        if (k_ >= 54) {
            v = -1e30f;
        } else {
            v = 0.f;
            if (q_ >= 5 && q_ < 54 && k_ >= 5) {
                int an = q_ - 5, am = k_ - 5;
                int iy = an / 7, ix = an % 7, jy = am / 7, jx = am % 7;
                v = rpb[((iy - jy + 6) * 13 + (ix - jx + 6)) * 3 + h];
                int whp = cls >> 1, wwp = cls & 1;
                int idn = (whp ? (iy < 4 ? 1 : 2) : 0) * 3 + (wwp ? (ix < 4 ? 1 : 2) : 0);
                int idm = (whp ? (jy < 4 ? 1 : 2) : 0) * 3 + (wwp ? (jx < 4 ? 1 : 2) : 0);
                if (idn != idm) v -= 100.f;
            }
        }
        tbl[i] = v;
    }
}

// token index in x for window token t of window (b, w=wh*8+ww); gather==scatter
__device__ __forceinline__ int src_index(int b, int w, int wh, int ww, int t)
{
    if (t < 5) return b * 3456 + w * 5 + t;
    int a = t - 5;
    int hi = wh * 7 + a / 7 + 3; if (hi >= 56) hi -= 56;
    int wi = ww * 7 + a % 7 + 3; if (wi >= 56) wi -= 56;
    return b * 3456 + 320 + hi * 56 + wi;
}

// ============ fully fused block, TWO windows, swapped-operand layout. ONE barrier.
__global__ __launch_bounds__(256, 2) void block_fused(const float* __restrict__ x,
                                                  const float* __restrict__ n1g, const float* __restrict__ n1b,
                                                  const float* __restrict__ qkvb, const float* __restrict__ tbl,
                                                  const float* __restrict__ projb,
                                                  const float* __restrict__ n2g, const float* __restrict__ n2b,
                                                  const float* __restrict__ fc1b, const float* __restrict__ fc2b,
                                                  const __bf16* __restrict__ wqkvT, const __bf16* __restrict__ wprojT,
                                                  const __bf16* __restrict__ w1T, const __bf16* __restrict__ w2T,
                                                  float* __restrict__ out)
{
    __shared__ __align__(16) char smem[79360];

    const int tid  = threadIdx.x;
    const int lane = tid & 63;
    const int wv   = tid >> 6;
    const int l15  = lane & 15;
    const int quad = lane >> 4;

    const int g  = blockIdx.x;          // 2048 blocks
    const int b  = g >> 5;
    const int wp = g & 31;              // window pair: windows 2*wp, 2*wp+1

    const int trow = wv * 16 + l15;     // this lane's token row (owned end-to-end)

    __bf16* kt[2];  __bf16* vTp[2];  __bf16* sw[2];
    int wI[2], whI[2], wwI[2], clsI[2], tsrc[2];
    #pragma unroll
    for (int wx = 0; wx < 2; wx++) {
        kt[wx]  = (__bf16*)(smem + wx * 13312);
        vTp[wx] = (__bf16*)(smem + 26624 + wx * 13056);
        sw[wx]  = (__bf16*)(smem + 52736 + (wv * 2 + wx) * 3328);
        int w = wp * 2 + wx;
        wI[wx] = w;  whI[wx] = w >> 3;  wwI[wx] = w & 7;
        clsI[wx] = ((whI[wx] == 7) ? 2 : 0) + ((wwI[wx] == 7) ? 1 : 0);
        tsrc[wx] = src_index(b, w, whI[wx], wwI[wx], trow < 54 ? trow : 53);
    }

    // P1: gather + LN1 into B-fragment registers (row=own token, k=quad*8-slices)
    bf16x8 xnfr[2][3];
    {
        float xv[2][24];
        #pragma unroll
        for (int wx = 0; wx < 2; wx++) {
            if (trow < 54) {
                const float* xr = x + (size_t)tsrc[wx] * 96 + quad * 8;
                #pragma unroll
                for (int ks = 0; ks < 3; ks++) {
                    float4 a0 = *(const float4*)(xr + ks * 32);
                    float4 a1 = *(const float4*)(xr + ks * 32 + 4);
                    float* p = xv[wx] + ks * 8;
                    p[0]=a0.x; p[1]=a0.y; p[2]=a0.z; p[3]=a0.w;
                    p[4]=a1.x; p[5]=a1.y; p[6]=a1.z; p[7]=a1.w;
                }
            } else {
                #pragma unroll
                for (int j = 0; j < 24; j++) xv[wx][j] = 0.f;
            }
        }
        float s[2] = {0.f, 0.f}, sq[2] = {0.f, 0.f};
        #pragma unroll
        for (int wx = 0; wx < 2; wx++)
            #pragma unroll
            for (int j = 0; j < 24; j++) { s[wx] += xv[wx][j]; sq[wx] += xv[wx][j] * xv[wx][j]; }
        #pragma unroll
        for (int wx = 0; wx < 2; wx++) { s[wx] += __shfl_xor(s[wx], 16, 64); sq[wx] += __shfl_xor(sq[wx], 16, 64); }
        #pragma unroll
        for (int wx = 0; wx < 2; wx++) { s[wx] += __shfl_xor(s[wx], 32, 64); sq[wx] += __shfl_xor(sq[wx], 32, 64); }
        float keep = (trow < 54) ? 1.f : 0.f;
        #pragma unroll
        for (int wx = 0; wx < 2; wx++) {
            float mean = s[wx] * (1.f / 96.f);
            float rstd = rsqrtf(sq[wx] * (1.f / 96.f) - mean * mean + 1e-5f);
            #pragma unroll
            for (int ks = 0; ks < 3; ks++) {
                const float* gp = n1g + ks * 32 + quad * 8;
                const float* bp = n1b + ks * 32 + quad * 8;
                float4 g0 = *(const float4*)(gp), g1 = *(const float4*)(gp + 4);
                float4 b0 = *(const float4*)(bp), b1 = *(const float4*)(bp + 4);
                float gg[8] = {g0.x,g0.y,g0.z,g0.w,g1.x,g1.y,g1.z,g1.w};
                float bb[8] = {b0.x,b0.y,b0.z,b0.w,b1.x,b1.y,b1.z,b1.w};
                #pragma unroll
                for (int j = 0; j < 8; j++)
                    xnfr[wx][ks][j] = (__bf16)(((xv[wx][ks*8+j] - mean) * rstd * gg[j] + bb[j]) * keep);
            }
        }
    }

    // P2a: q,k SWAPPED (A=W rows, B=tokens): lane gets token=l15, cols nt*16+quad*4+r.
    #pragma unroll
    for (int nt = 0; nt < 12; nt++) {
        const __bf16* br = wqkvT + (size_t)(nt * 16 + l15) * 96 + quad * 8;
        bf16x8 b0 = *(const bf16x8*)(br);
        bf16x8 b1 = *(const bf16x8*)(br + 32);
        bf16x8 b2 = *(const bf16x8*)(br + 64);
        float4 bias4 = *(const float4*)(qkvb + nt * 16 + quad * 4);
        if (nt < 6) { bias4.x *= SCALE_Q; bias4.y *= SCALE_Q; bias4.z *= SCALE_Q; bias4.w *= SCALE_Q; }
        #pragma unroll
        for (int wx = 0; wx < 2; wx++) {
            f32x4 acc = {0.f, 0.f, 0.f, 0.f};
            acc = MFMA16(b0, xnfr[wx][0], acc);
            acc = MFMA16(b1, xnfr[wx][1], acc);
            acc = MFMA16(b2, xnfr[wx][2], acc);
            bf16x4 pk;
            pk[0] = (__bf16)(acc[0] + bias4.x);
            pk[1] = (__bf16)(acc[1] + bias4.y);
            pk[2] = (__bf16)(acc[2] + bias4.z);
            pk[3] = (__bf16)(acc[3] + bias4.w);
            if (nt < 6) *(bf16x4*)(sw[wx] + l15 * KST + nt * 16 + quad * 4) = pk;            // q -> scratch
            else        *(bf16x4*)(kt[wx] + (size_t)trow * KST + (nt - 6) * 16 + quad * 4) = pk; // k -> kt[tok][kc]
        }
    }
    bf16x8 aq[2][3];                    // own-token q as B-frag (in-wave lgkmcnt RAW)
    #pragma unroll
    for (int wx = 0; wx < 2; wx++)
        #pragma unroll
        for (int h = 0; h < 3; h++)
            aq[wx][h] = *(const bf16x8*)(sw[wx] + l15 * KST + h * 32 + quad * 8);

    // P2b: v UNSWAPPED (A=tokens, B=W): lane gets vc=l15-col, tokens quad*4+r -> vT[d][tok] b64
    #pragma unroll
    for (int nt = 12; nt < 18; nt++) {
        const __bf16* br = wqkvT + (size_t)(nt * 16 + l15) * 96 + quad * 8;
        bf16x8 b0 = *(const bf16x8*)(br);
        bf16x8 b1 = *(const bf16x8*)(br + 32);
        bf16x8 b2 = *(const bf16x8*)(br + 64);
        float bias = qkvb[nt * 16 + l15];
        int vc = nt * 16 + l15 - 192;
        #pragma unroll
        for (int wx = 0; wx < 2; wx++) {
            f32x4 acc = {0.f, 0.f, 0.f, 0.f};
            acc = MFMA16(xnfr[wx][0], b0, acc);
            acc = MFMA16(xnfr[wx][1], b1, acc);
            acc = MFMA16(xnfr[wx][2], b2, acc);
            bf16x4 pk;
            pk[0] = (__bf16)(acc[0] + bias);
            pk[1] = (__bf16)(acc[1] + bias);
            pk[2] = (__bf16)(acc[2] + bias);
            pk[3] = (__bf16)(acc[3] + bias);
            *(bf16x4*)(vTp[wx] + (size_t)vc * VP + wv * 16 + quad * 4) = pk;
        }
    }
    __syncthreads();   // barrier 1 (the ONLY barrier): kt/vT staged cross-wave

    // P3+P4+P5 per head. QK SWAPPED: mfma(K,Q) -> lane: q-token=l15, k=nt*16+quad*4+r.
    f32x4 oacc[2][6];
    #pragma unroll
    for (int wx = 0; wx < 2; wx++)
        #pragma unroll
        for (int i = 0; i < 6; i++) oacc[wx][i] = (f32x4){0.f, 0.f, 0.f, 0.f};

    #pragma unroll
    for (int h = 0; h < 3; h++) {
        float sv[2][4][4];
        #pragma unroll
        for (int wx = 0; wx < 2; wx++) {
            const float* tbh = tbl + (size_t)(clsI[wx] * 3 + h) * 4096 + trow * 64 + quad * 4;
            #pragma unroll
            for (int nt = 0; nt < 4; nt++) {
                bf16x8 ak = *(const bf16x8*)(kt[wx] + (nt * 16 + l15) * KST + h * 32 + quad * 8);
                f32x4 c = {0.f, 0.f, 0.f, 0.f};
                c = MFMA16(ak, aq[wx][h], c);
                float4 tv = *(const float4*)(tbh + nt * 16);
                sv[wx][nt][0] = c[0] + tv.x;
                sv[wx][nt][1] = c[1] + tv.y;
                sv[wx][nt][2] = c[2] + tv.z;
                sv[wx][nt][3] = c[3] + tv.w;
            }
        }
        // softmax: full k-row = 16 in-lane values + cross-quad (2 shuffles each)
        #pragma unroll
        for (int wx = 0; wx < 2; wx++) {
            float mx = sv[wx][0][0];
            #pragma unroll
            for (int nt = 0; nt < 4; nt++)
                #pragma unroll
                for (int r = 0; r < 4; r++) mx = fmaxf(mx, sv[wx][nt][r]);
            mx = fmaxf(mx, __shfl_xor(mx, 16, 64));
            mx = fmaxf(mx, __shfl_xor(mx, 32, 64));
            float ps[4][4]; float sum = 0.f;
            #pragma unroll
            for (int nt = 0; nt < 4; nt++)
                #pragma unroll
                for (int r = 0; r < 4; r++) { ps[nt][r] = __expf(sv[wx][nt][r] - mx); sum += ps[nt][r]; }
            sum += __shfl_xor(sum, 16, 64);
            sum += __shfl_xor(sum, 32, 64);
            float inv = 1.f / sum;
            #pragma unroll
            for (int nt = 0; nt < 4; nt++) {
                bf16x4 pk;
                pk[0] = (__bf16)(ps[nt][0] * inv);
                pk[1] = (__bf16)(ps[nt][1] * inv);
                pk[2] = (__bf16)(ps[nt][2] * inv);
                pk[3] = (__bf16)(ps[nt][3] * inv);
                *(bf16x4*)(sw[wx] + l15 * KST + nt * 16 + quad * 4) = pk;   // P[q-tok l15][k]
            }
        }
        // PV SWAPPED: mfma(Vt, P): A=vT rows (d), B=P rows (q-tokens)
        #pragma unroll
        for (int wx = 0; wx < 2; wx++) {
            bf16x8 pa0 = *(const bf16x8*)(sw[wx] + l15 * KST + quad * 8);
            bf16x8 pa1 = *(const bf16x8*)(sw[wx] + l15 * KST + 32 + quad * 8);
            #pragma unroll
            for (int dt = 0; dt < 2; dt++) {
                const __bf16* vr = vTp[wx] + (h * 32 + dt * 16 + l15) * VP;
                f32x4 acc = oacc[wx][h * 2 + dt];
                acc = MFMA16(*(const bf16x8*)(vr + quad * 8), pa0, acc);
                acc = MFMA16(*(const bf16x8*)(vr + 32 + quad * 8), pa1, acc);
                oacc[wx][h * 2 + dt] = acc;
            }
        }
    }

    // attn-out: lane holds token=l15, d-cols i*16+quad*4+r -> b64 roundtrip to B-frags
    bf16x8 ofr[2][3];
    #pragma unroll
    for (int wx = 0; wx < 2; wx++) {
        #pragma unroll
        for (int i = 0; i < 6; i++) {
            bf16x4 pk;
            pk[0] = (__bf16)oacc[wx][i][0];
            pk[1] = (__bf16)oacc[wx][i][1];
            pk[2] = (__bf16)oacc[wx][i][2];
            pk[3] = (__bf16)oacc[wx][i][3];
            *(bf16x4*)(sw[wx] + l15 * KST + i * 16 + quad * 4) = pk;
        }
        #pragma unroll
        for (int ks = 0; ks < 3; ks++)
            ofr[wx][ks] = *(const bf16x8*)(sw[wx] + l15 * KST + ks * 32 + quad * 8);
    }

    // P6: proj SWAPPED -> av in REGISTERS (token=l15, cols nt*16+quad*4+r)
    float av[2][24];
    #pragma unroll
    for (int nt = 0; nt < 6; nt++) {
        const __bf16* br = wprojT + (size_t)(nt * 16 + l15) * 96 + quad * 8;
        bf16x8 b0 = *(const bf16x8*)(br);
        bf16x8 b1 = *(const bf16x8*)(br + 32);
        bf16x8 b2 = *(const bf16x8*)(br + 64);
        float4 pb = *(const float4*)(projb + nt * 16 + quad * 4);
        #pragma unroll
        for (int wx = 0; wx < 2; wx++) {
            f32x4 acc = {0.f, 0.f, 0.f, 0.f};
            acc = MFMA16(b0, ofr[wx][0], acc);
            acc = MFMA16(b1, ofr[wx][1], acc);
            acc = MFMA16(b2, ofr[wx][2], acc);
            av[wx][nt*4+0] = acc[0] + pb.x;
            av[wx][nt*4+1] = acc[1] + pb.y;
            av[wx][nt*4+2] = acc[2] + pb.z;
            av[wx][nt*4+3] = acc[3] + pb.w;
        }
    }

    // M1: y = x + a (registers); LN2 via quad shuffles; yn -> B-frag roundtrip
    float yv[2][24];
    float s2[2] = {0.f, 0.f}, sq2[2] = {0.f, 0.f};
    #pragma unroll
    for (int wx = 0; wx < 2; wx++) {
        const float* xr = x + (size_t)tsrc[wx] * 96 + quad * 4;
        #pragma unroll
        for (int nt = 0; nt < 6; nt++) {
            float4 xa = *(const float4*)(xr + nt * 16);
            float* yp = yv[wx] + nt * 4;
            yp[0] = xa.x + av[wx][nt*4+0];
            yp[1] = xa.y + av[wx][nt*4+1];
            yp[2] = xa.z + av[wx][nt*4+2];
            yp[3] = xa.w + av[wx][nt*4+3];
            #pragma unroll
            for (int j = 0; j < 4; j++) { s2[wx] += yp[j]; sq2[wx] += yp[j] * yp[j]; }
        }
    }
    #pragma unroll
    for (int wx = 0; wx < 2; wx++) { s2[wx] += __shfl_xor(s2[wx], 16, 64); sq2[wx] += __shfl_xor(sq2[wx], 16, 64); }
    #pragma unroll
    for (int wx = 0; wx < 2; wx++) { s2[wx] += __shfl_xor(s2[wx], 32, 64); sq2[wx] += __shfl_xor(sq2[wx], 32, 64); }

    bf16x8 afr[2][3];
    #pragma unroll
    for (int wx = 0; wx < 2; wx++) {
        float mean = s2[wx] * (1.f / 96.f);
        float rstd = rsqrtf(sq2[wx] * (1.f / 96.f) - mean * mean + 1e-5f);
        #pragma unroll
        for (int nt = 0; nt < 6; nt++) {
            float4 gg = *(const float4*)(n2g + nt * 16 + quad * 4);
            float4 bb = *(const float4*)(n2b + nt * 16 + quad * 4);
            bf16x4 pk;
            pk[0] = (__bf16)((yv[wx][nt*4+0] - mean) * rstd * gg.x + bb.x);
            pk[1] = (__bf16)((yv[wx][nt*4+1] - mean) * rstd * gg.y + bb.y);
            pk[2] = (__bf16)((yv[wx][nt*4+2] - mean) * rstd * gg.z + bb.z);
            pk[3] = (__bf16)((yv[wx][nt*4+3] - mean) * rstd * gg.w + bb.w);
            *(bf16x4*)(sw[wx] + l15 * KST + nt * 16 + quad * 4) = pk;
        }
        #pragma unroll
        for (int ks = 0; ks < 3; ks++)
            afr[wx][ks] = *(const bf16x8*)(sw[wx] + l15 * KST + ks * 32 + quad * 8);
    }

    // M2+M3 fused per 32-wide hidden chunk: fc1 SWAPPED + GELU -> b64 roundtrip -> fc2 SWAPPED
    f32x4 acc2[2][6];
    #pragma unroll
    for (int wx = 0; wx < 2; wx++)
        #pragma unroll
        for (int nt = 0; nt < 6; nt++) acc2[wx][nt] = (f32x4){0.f, 0.f, 0.f, 0.f};

    #pragma unroll
    for (int np = 0; np < 12; np++) {
        int reg = (np % 3) * 32;                           // cycle 3 scratch regions for pipelining
        #pragma unroll
        for (int u = 0; u < 2; u++) {
            int ntx = np * 2 + u;
            const __bf16* br = w1T + (size_t)(ntx * 16 + l15) * 96 + quad * 8;
            bf16x8 b0 = *(const bf16x8*)(br);
            bf16x8 b1 = *(const bf16x8*)(br + 32);
            bf16x8 b2 = *(const bf16x8*)(br + 64);
            float4 fb = *(const float4*)(fc1b + ntx * 16 + quad * 4);
            float fbv[4] = {fb.x, fb.y, fb.z, fb.w};
            #pragma unroll
            for (int wx = 0; wx < 2; wx++) {
                f32x4 acc = {0.f, 0.f, 0.f, 0.f};
                acc = MFMA16(b0, afr[wx][0], acc);
                acc = MFMA16(b1, afr[wx][1], acc);
                acc = MFMA16(b2, afr[wx][2], acc);
                bf16x4 pk;
                #pragma unroll
                for (int r = 0; r < 4; r++) {
                    float v  = acc[r] + fbv[r];
                    float u2 = -1.5957691216057308f * v * (1.f + 0.044715f * v * v);
                    float t  = __expf(u2);
                    pk[r] = (__bf16)(v * __builtin_amdgcn_rcpf(1.f + t));
                }
                *(bf16x4*)(sw[wx] + l15 * KST + reg + u * 16 + quad * 4) = pk;
            }
        }
        bf16x8 hc0 = *(const bf16x8*)(sw[0] + l15 * KST + reg + quad * 8);
        bf16x8 hc1 = *(const bf16x8*)(sw[1] + l15 * KST + reg + quad * 8);
        #pragma unroll
        for (int nt = 0; nt < 6; nt++) {
            bf16x8 wb = *(const bf16x8*)(w2T + (size_t)(nt * 16 + l15) * 384 + np * 32 + quad * 8);
            acc2[0][nt] = MFMA16(wb, hc0, acc2[0][nt]);
            acc2[1][nt] = MFMA16(wb, hc1, acc2[1][nt]);
        }
    }

    // M4: final = y + fc2out + fc2b, straight from registers (token=l15, cols nt*16+quad*4+r)
    #pragma unroll
    for (int nt = 0; nt < 6; nt++) {
        float4 fb = *(const float4*)(fc2b + nt * 16 + quad * 4);
        #pragma unroll
        for (int wx = 0; wx < 2; wx++) {
            if (trow < 54) {
                float4 o;
                o.x = yv[wx][nt*4+0] + acc2[wx][nt][0] + fb.x;
                o.y = yv[wx][nt*4+1] + acc2[wx][nt][1] + fb.y;
                o.z = yv[wx][nt*4+2] + acc2[wx][nt][2] + fb.z;
                o.w = yv[wx][nt*4+3] + acc2[wx][nt][3] + fb.w;
                *(float4*)(out + (size_t)tsrc[wx] * 96 + nt * 16 + quad * 4) = o;
            }
        }
    }
}

extern "C" void kernel_launch(void* const* d_in, const int* in_sizes, int n_in,
                              void* d_out, int out_size, void* d_ws, size_t ws_size,
                              hipStream_t stream)
{
    const float* x      = (const float*)d_in[0];
    const float* n1g    = (const float*)d_in[1];
    const float* n1b    = (const float*)d_in[2];
    const float* qkv_w  = (const float*)d_in[3];
    const float* qkv_b  = (const float*)d_in[4];
    const float* rpb    = (const float*)d_in[5];
    const float* proj_w = (const float*)d_in[6];
    const float* proj_b = (const float*)d_in[7];
    const float* n2g    = (const float*)d_in[8];
    const float* n2b    = (const float*)d_in[9];
    const float* fc1_w  = (const float*)d_in[10];
    const float* fc1_b  = (const float*)d_in[11];
    const float* fc2_w  = (const float*)d_in[12];
    const float* fc2_b  = (const float*)d_in[13];

    __bf16* ws     = (__bf16*)d_ws;
    __bf16* wqkvT  = ws;            // [288][96]
    __bf16* wprojT = ws + 27648;    // [96][96]
    __bf16* w1T    = ws + 36864;    // [384][96]
    __bf16* w2T    = ws + 73728;    // [96][384]
    float*  tbl    = (float*)((char*)d_ws + 221184);   // [4][3][64][64] fp32, 196608 B

    float* out = (float*)d_out;

    hipLaunchKernelGGL(prep, dim3(432), dim3(256), 0, stream,
                       qkv_w, proj_w, fc1_w, fc2_w, rpb, ws, tbl);
    hipLaunchKernelGGL(block_fused, dim3(2048), dim3(256), 0, stream,
                       x, n1g, n1b, qkv_b, tbl, proj_b, n2g, n2b, fc1_b, fc2_b,
                       wqkvT, wprojT, w1T, w2T, out);
}